// Round 2
// baseline (95.139 us; speedup 1.0000x reference)
//
#include <hip/hip_runtime.h>

#define BN_EPS 1e-5f

constexpr int Bb = 2;
constexpr int Cc = 64;
constexpr int Nn = 32768;
constexpr int Kk = 16;
constexpr int Oo = 64;

typedef __attribute__((ext_vector_type(8))) short v8s;   // 8 x bf16 (4 VGPRs)
typedef __attribute__((ext_vector_type(4))) float v4f;   // MFMA C/D / NT stores
typedef __attribute__((ext_vector_type(4))) int   v4i;   // NT idx loads

__device__ __forceinline__ unsigned short f2bf(float f) {
    unsigned u = __float_as_uint(f);
    return (unsigned short)((u + 0x7FFFu + ((u >> 16) & 1u)) >> 16);  // RNE
}

// Kernel 1: MFMA gemm, A = W (m=o), B = feature (j=n) -> D row = o, each lane
// holds 4 consecutive o per tile -> ushort4 epilogue stores.
// R8: 256-n tile per block (256 blocks x 1024 thr): W staged ONCE per 256 n
// (4 loads/thread vs 16), 4x fewer blocks. 16 waves each own one 16-n strip.
// b = blk&1: round-robin blk->XCD gives one batch per XCD parity.
// [FROZEN this round for clean A/B on kernel 2]
__global__ __launch_bounds__(1024) void spe_gemm_mfma(
    const float* __restrict__ feature, const float* __restrict__ W,
    const float* __restrict__ gamma, const float* __restrict__ beta,
    const float* __restrict__ rmean, const float* __restrict__ rvar,
    unsigned short* __restrict__ t)
{
    __shared__ unsigned short Wl[64][68];   // Wl[o][c], +4 pad
    __shared__ float invs[64], biass[64];
    const int tid = threadIdx.x;
    const int blk = blockIdx.x;             // 256 = 2 batches x 128 tiles
    const int b   = blk & 1;
    const int n0  = (blk >> 1) << 8;        // 256-n tile

    // stage W (coalesced, 4 rounds) + BN precompute (threads 0-63)
    #pragma unroll
    for (int j = 0; j < 4; ++j) {
        const int i = j * 1024 + tid;
        Wl[i >> 6][i & 63] = f2bf(W[i]);
    }
    if (tid < 64) {
        const float iv = gamma[tid] / sqrtf(rvar[tid] + BN_EPS);
        invs[tid]  = iv;
        biass[tid] = beta[tid] - rmean[tid] * iv;
    }

    const int wv   = tid >> 6;      // wave 0..15: n-rows [wv*16, wv*16+16)
    const int lane = tid & 63;
    const int q    = lane >> 4;     // k-chunk q*8 within K=32
    const int r16  = lane & 15;

    union U { ushort4 u4[2]; unsigned short us[8]; v8s v; };

    // B-frags (feature) from global: lane j=r16 -> n, k = q*8+jj (+0 / +32)
    const int nb = n0 + wv * 16 + r16;
    const float* fp = feature + (size_t)b * Cc * Nn + nb;
    U bf0, bf1;
    #pragma unroll
    for (int jj = 0; jj < 8; ++jj) {
        bf0.us[jj] = f2bf(fp[(size_t)(q * 8 + jj) * Nn]);
        bf1.us[jj] = f2bf(fp[(size_t)(q * 8 + jj + 32) * Nn]);
    }
    __syncthreads();

    #pragma unroll
    for (int ot = 0; ot < 4; ++ot) {
        const int oa = ot * 16 + r16;       // A row m = o
        U af0, af1;
        af0.u4[0] = *(const ushort4*)&Wl[oa][q * 8];
        af0.u4[1] = *(const ushort4*)&Wl[oa][q * 8 + 4];
        af1.u4[0] = *(const ushort4*)&Wl[oa][q * 8 + 32];
        af1.u4[1] = *(const ushort4*)&Wl[oa][q * 8 + 36];

        v4f c = {0.f, 0.f, 0.f, 0.f};
        c = __builtin_amdgcn_mfma_f32_16x16x32_bf16(af0.v, bf0.v, c, 0, 0, 0);
        c = __builtin_amdgcn_mfma_f32_16x16x32_bf16(af1.v, bf1.v, c, 0, 0, 0);

        // D[row = o = ot*16 + q*4 + r][col = n = nb]; BN+ReLU, ushort4 store
        const int ob4 = ot * 16 + q * 4;
        const float4 iv4 = *(const float4*)&invs[ob4];
        const float4 bi4 = *(const float4*)&biass[ob4];

        ushort4 ov;
        ov.x = f2bf(fmaxf(fmaf(iv4.x, c[0], bi4.x), 0.0f));
        ov.y = f2bf(fmaxf(fmaf(iv4.y, c[1], bi4.y), 0.0f));
        ov.z = f2bf(fmaxf(fmaf(iv4.z, c[2], bi4.z), 0.0f));
        ov.w = f2bf(fmaxf(fmaf(iv4.w, c[3], bi4.w), 0.0f));
        *(ushort4*)&t[((size_t)b * Nn + nb) * 64 + ob4] = ov;
    }
}

// Kernel 2: out[b][o][n] = t[b][n][o] + sum_j t[b][idx[b][n][j]][o]
// 8 waves/block (512 thr), wave owns 8 points: lane=(p,e), p=point 0..7,
// e=o-octet. 17 x 16B gathers per lane, ALL issued before accumulation.
// R9/R10: protect the per-XCD L2 for t (the only reused data):
//  - idx loads + out stores are NON-TEMPORAL (streams no longer evict t)
//    [R10: via ext_vector types — HIP_vector_type rejected by the builtin]
//  - idx read directly per-lane as 4x v4i broadcast loads (8 lanes share
//    the same 16B -> HW merges); drops the int2 + 16x ds_bpermute chain
//  - out stores widened to float4 (2 NT stores/thread vs 8 scalar)
//  - launch_bounds(512,4): VGPR cap 128 (~110 live) -> 2 blocks/CU,
//    2x outstanding gathers while t lines age in L2
__global__ __launch_bounds__(512, 4) void spe_gather_sum(
    const unsigned short* __restrict__ t, const int* __restrict__ idx,
    float* __restrict__ out)
{
    __shared__ float s[64 * 65];      // stride 65
    const int tid  = threadIdx.x;
    const int wv   = tid >> 6;        // 0..7
    const int lane = tid & 63;
    const int p    = lane >> 3;       // point 0..7
    const int e    = lane & 7;        // o-octet (o = e*8 .. e*8+8)
    const int blk  = blockIdx.x;
    const int b    = blk & 1;
    const int n0   = (blk >> 1) << 6;
    const int ng   = n0 + wv * 8;

    const unsigned short* tb = t + (size_t)b * Nn * 64;

    // idx for this lane's point, 4 x v4i = 16 ints, NT (no L2 allocate).
    // 8 e-lanes issue identical addresses -> merged + broadcast in TA/L1.
    const v4i* ip = (const v4i*)(idx + ((size_t)b * Nn + ng + p) * Kk);
    union I { v4i v4[4]; int a[16]; } ii;
    ii.v4[0] = __builtin_nontemporal_load(ip + 0);
    ii.v4[1] = __builtin_nontemporal_load(ip + 1);
    ii.v4[2] = __builtin_nontemporal_load(ip + 2);
    ii.v4[3] = __builtin_nontemporal_load(ip + 3);

    // all 17 gathers issued back-to-back (16B each, independent, cacheable:
    // t is the reused working set we want resident in L2)
    uint4 v[17];
    v[0] = *(const uint4*)&tb[(size_t)(ng + p) * 64 + e * 8];
    #pragma unroll
    for (int j = 0; j < 16; ++j)
        v[j + 1] = *(const uint4*)&tb[(size_t)ii.a[j] * 64 + e * 8];

    // fp32 accumulate (unpack bf16 pairs: 1 shl / 1 and each)
    float acc[8] = {0.f, 0.f, 0.f, 0.f, 0.f, 0.f, 0.f, 0.f};
    #pragma unroll
    for (int j = 0; j < 17; ++j) {
        acc[0] += __uint_as_float(v[j].x << 16);
        acc[1] += __uint_as_float(v[j].x & 0xFFFF0000u);
        acc[2] += __uint_as_float(v[j].y << 16);
        acc[3] += __uint_as_float(v[j].y & 0xFFFF0000u);
        acc[4] += __uint_as_float(v[j].z << 16);
        acc[5] += __uint_as_float(v[j].z & 0xFFFF0000u);
        acc[6] += __uint_as_float(v[j].w << 16);
        acc[7] += __uint_as_float(v[j].w & 0xFFFF0000u);
    }

    float* sp = &s[(wv * 8 + p) * 65 + e * 8];
    #pragma unroll
    for (int i = 0; i < 8; ++i) sp[i] = acc[i];
    __syncthreads();

    // transpose write-out: tau = (o, 4n-group); lanes step the n-group ->
    // 16 consecutive lanes store 256B contiguous; NT v4f stores.
    // LDS read banks: dword addr (g*4+k)*65 + o -> (4g+k+o) mod 32: 2-way, free.
    #pragma unroll
    for (int i = 0; i < 2; ++i) {
        const int tau = tid + i * 512;
        const int o   = tau >> 4;          // 0..63
        const int g   = tau & 15;          // n-group of 4
        v4f val;
        val[0] = s[(g * 4 + 0) * 65 + o];
        val[1] = s[(g * 4 + 1) * 65 + o];
        val[2] = s[(g * 4 + 2) * 65 + o];
        val[3] = s[(g * 4 + 3) * 65 + o];
        __builtin_nontemporal_store(val,
            (v4f*)&out[((size_t)b * Oo + o) * Nn + n0 + g * 4]);
    }
}

extern "C" void kernel_launch(void* const* d_in, const int* in_sizes, int n_in,
                              void* d_out, int out_size, void* d_ws, size_t ws_size,
                              hipStream_t stream) {
    const float* feature = (const float*)d_in[0];
    const int*   nidx    = (const int*)d_in[1];
    const float* W       = (const float*)d_in[2];
    const float* gamma   = (const float*)d_in[3];
    const float* beta    = (const float*)d_in[4];
    const float* rmean   = (const float*)d_in[5];
    const float* rvar    = (const float*)d_in[6];
    float* out = (float*)d_out;
    unsigned short* t = (unsigned short*)d_ws;   // B*N*O*2 = 8 MiB bf16

    spe_gemm_mfma<<<Bb * (Nn / 256), 1024, 0, stream>>>(feature, W, gamma, beta, rmean, rvar, t);
    spe_gather_sum<<<Bb * (Nn / 64), 512, 0, stream>>>(t, nidx, out);
}